// Round 1
// baseline (519.791 us; speedup 1.0000x reference)
//
#include <hip/hip_runtime.h>

typedef __attribute__((ext_vector_type(8))) short short8;
typedef __attribute__((ext_vector_type(4))) float f32x4;

__device__ __forceinline__ unsigned short f2bf(float f) {
    unsigned int u = __float_as_uint(f);
    u += 0x7FFFu + ((u >> 16) & 1u);   // round-to-nearest-even
    return (unsigned short)(u >> 16);
}

// swizzle for [R][64] bf16 row-major (128B row stride): XOR 16B-slot by row&7
__device__ __forceinline__ int swz64(int row, int col) {
    return (row << 6) + (col ^ ((row & 7) << 3));
}
// swizzle for [64][256] bf16 row-major (512B row stride)
__device__ __forceinline__ int swzX(int row, int col) {
    return (row << 8) + (col ^ ((row & 7) << 3));
}

// d_ws layout: [0 .. 196608)   wqkvT  bf16 [768][256]   (wqkvT[n][k] = w_qkv[k][n])
//              [196608 .. 262144) wprojT bf16 [256][256]
__global__ void prep_w(const float* __restrict__ wqkv, const float* __restrict__ wproj,
                       unsigned short* __restrict__ wT) {
    int idx = blockIdx.x * 256 + threadIdx.x;   // 0 .. 262143
    if (idx < 768 * 256) {
        int n = idx >> 8, k = idx & 255;
        wT[idx] = f2bf(wqkv[k * 768 + n]);
    } else {
        int r = idx - 768 * 256;
        int n = r >> 8, k = r & 255;
        wT[idx] = f2bf(wproj[(k << 8) + n]);
    }
}

__global__ __launch_bounds__(256, 2)
void winattn(const float* __restrict__ x,
             const float* __restrict__ bqkv,
             const float* __restrict__ bproj,
             const unsigned short* __restrict__ wqkvT,
             const unsigned short* __restrict__ wprojT,
             float* __restrict__ out)
{
    // LDS: 32K + 8K + 8K + 8K = 56KB -> 2 blocks/CU
    __shared__ unsigned short x_lds[64 * 256];  // x window, bf16, swizzled
    __shared__ unsigned short bufA[64 * 64];    // q -> P(head even) -> o
    __shared__ unsigned short bufB[64 * 64];    // k -> P(head odd)
    __shared__ unsigned short vT[64 * 64];      // v transposed [d_pair][token]

    const int tid  = threadIdx.x;
    const int wave = tid >> 6;
    const int lane = tid & 63;
    const int g    = lane >> 4;   // k-group 0..3
    const int q16  = lane & 15;

    const int widx = blockIdx.x;
    const int b  = widx >> 10;
    const int wh = (widx >> 5) & 31;
    const int ww = widx & 31;

    // ---- stage x window -> LDS bf16 (swizzled) ----
    {
        const int t  = tid >> 2;           // token 0..63
        const int c0 = (tid & 3) << 6;     // channel base
        const int hr = (wh << 3) + (t >> 3);
        const int wc = (ww << 3) + (t & 7);
        const float* rowp = x + (((size_t)b * 256 + hr) * 256 + wc) * 256;
        #pragma unroll
        for (int u = 0; u < 8; ++u) {
            const float4 f0 = *reinterpret_cast<const float4*>(rowp + c0 + u * 8);
            const float4 f1 = *reinterpret_cast<const float4*>(rowp + c0 + u * 8 + 4);
            short8 v;
            v[0] = (short)f2bf(f0.x); v[1] = (short)f2bf(f0.y);
            v[2] = (short)f2bf(f0.z); v[3] = (short)f2bf(f0.w);
            v[4] = (short)f2bf(f1.x); v[5] = (short)f2bf(f1.y);
            v[6] = (short)f2bf(f1.z); v[7] = (short)f2bf(f1.w);
            *reinterpret_cast<short8*>(&x_lds[swzX(t, c0 + u * 8)]) = v;
        }
    }
    __syncthreads();

    const f32x4 fzero = {0.f, 0.f, 0.f, 0.f};
    f32x4 acc_p[4][4];                      // proj accumulators [Mtile][Ntile]
    #pragma unroll
    for (int i = 0; i < 4; ++i)
        #pragma unroll
        for (int j = 0; j < 4; ++j) acc_p[i][j] = fzero;

    const int hh    = wave >> 1;            // head-within-pair this wave serves
    const int i0    = (wave & 1) << 1;      // row-half: M-tiles {i0, i0+1}
    const int dbase = hh << 5;              // head d-offset within pair (0 / 32)
    const float scale = 0.17677669529663687f;  // 1/sqrt(32)

    for (int p = 0; p < 4; ++p) {           // head pair {2p, 2p+1}
        // ===== QKV chunk GEMM: M=64, N=192 (q64,k64,v64), K=256 =====
        f32x4 aq[4], ak[4], av[4];
        #pragma unroll
        for (int i = 0; i < 4; ++i) { aq[i] = fzero; ak[i] = fzero; av[i] = fzero; }
        const int nq = (p << 6) + (wave << 4) + q16;   // global q column
        const unsigned short* wq = wqkvT + (size_t)nq * 256;
        const unsigned short* wk = wqkvT + (size_t)(256 + nq) * 256;
        const unsigned short* wv = wqkvT + (size_t)(512 + nq) * 256;
        #pragma unroll
        for (int ks = 0; ks < 8; ++ks) {
            const int kc = (ks << 5) + (g << 3);
            const short8 bq = *reinterpret_cast<const short8*>(wq + kc);
            const short8 bk = *reinterpret_cast<const short8*>(wk + kc);
            const short8 bv = *reinterpret_cast<const short8*>(wv + kc);
            #pragma unroll
            for (int i = 0; i < 4; ++i) {
                const short8 a = *reinterpret_cast<const short8*>(&x_lds[swzX((i << 4) + q16, kc)]);
                aq[i] = __builtin_amdgcn_mfma_f32_16x16x32_bf16(a, bq, aq[i], 0, 0, 0);
                ak[i] = __builtin_amdgcn_mfma_f32_16x16x32_bf16(a, bk, ak[i], 0, 0, 0);
                av[i] = __builtin_amdgcn_mfma_f32_16x16x32_bf16(a, bv, av[i], 0, 0, 0);
            }
        }
        {
            const float biasq = bqkv[nq];
            const float biask = bqkv[256 + nq];
            const float biasv = bqkv[512 + nq];
            const int cloc = (wave << 4) + q16;   // pair-local column 0..63
            #pragma unroll
            for (int i = 0; i < 4; ++i) {
                #pragma unroll
                for (int r = 0; r < 4; ++r) {
                    const int t = (i << 4) + (g << 2) + r;
                    bufA[swz64(t, cloc)] = f2bf(aq[i][r] + biasq);   // q[t][d]
                    bufB[swz64(t, cloc)] = f2bf(ak[i][r] + biask);   // k[t][d]
                    vT[swz64(cloc, t)]   = f2bf(av[i][r] + biasv);   // v^T[d][t]
                }
            }
        }
        __syncthreads();

        // ===== S = scale * q k^T (wave: head hh, rows 32*(wave&1)..+32) =====
        f32x4 s[2][4];
        {
            const int kc = dbase + (g << 3);
            const short8 qf0 = *reinterpret_cast<const short8*>(&bufA[swz64((i0 << 4) + q16, kc)]);
            const short8 qf1 = *reinterpret_cast<const short8*>(&bufA[swz64(((i0 + 1) << 4) + q16, kc)]);
            #pragma unroll
            for (int j = 0; j < 4; ++j) {
                const short8 kf = *reinterpret_cast<const short8*>(&bufB[swz64((j << 4) + q16, kc)]);
                s[0][j] = __builtin_amdgcn_mfma_f32_16x16x32_bf16(qf0, kf, fzero, 0, 0, 0);
                s[1][j] = __builtin_amdgcn_mfma_f32_16x16x32_bf16(qf1, kf, fzero, 0, 0, 0);
            }
        }
        // ===== softmax over key axis (cols spread over q16 lanes x 4 j-tiles) =====
        float pe[2][4][4];
        #pragma unroll
        for (int ii = 0; ii < 2; ++ii) {
            #pragma unroll
            for (int r = 0; r < 4; ++r) {
                const float v0 = s[ii][0][r] * scale;
                const float v1 = s[ii][1][r] * scale;
                const float v2 = s[ii][2][r] * scale;
                const float v3 = s[ii][3][r] * scale;
                float m = fmaxf(fmaxf(v0, v1), fmaxf(v2, v3));
                #pragma unroll
                for (int d = 1; d < 16; d <<= 1) m = fmaxf(m, __shfl_xor(m, d, 64));
                const float e0 = __expf(v0 - m), e1 = __expf(v1 - m);
                const float e2 = __expf(v2 - m), e3 = __expf(v3 - m);
                float sum = e0 + e1 + e2 + e3;
                #pragma unroll
                for (int d = 1; d < 16; d <<= 1) sum += __shfl_xor(sum, d, 64);
                const float inv = 1.f / sum;
                pe[ii][0][r] = e0 * inv; pe[ii][1][r] = e1 * inv;
                pe[ii][2][r] = e2 * inv; pe[ii][3][r] = e3 * inv;
            }
        }
        __syncthreads();   // all q/k reads done before P overwrites bufA/bufB
        unsigned short* Pb = hh ? bufB : bufA;
        #pragma unroll
        for (int ii = 0; ii < 2; ++ii)
            #pragma unroll
            for (int j = 0; j < 4; ++j)
                #pragma unroll
                for (int r = 0; r < 4; ++r)
                    Pb[swz64(((i0 + ii) << 4) + (g << 2) + r, (j << 4) + q16)] = f2bf(pe[ii][j][r]);
        __syncthreads();

        // ===== O = P @ V  (M=wave's 32 rows, N=32 head dims, K=64 tokens) =====
        f32x4 o_[2][2];
        #pragma unroll
        for (int ii = 0; ii < 2; ++ii)
            #pragma unroll
            for (int jo = 0; jo < 2; ++jo) o_[ii][jo] = fzero;
        #pragma unroll
        for (int ks = 0; ks < 2; ++ks) {
            const int kc = (ks << 5) + (g << 3);
            const short8 a0 = *reinterpret_cast<const short8*>(&Pb[swz64((i0 << 4) + q16, kc)]);
            const short8 a1 = *reinterpret_cast<const short8*>(&Pb[swz64(((i0 + 1) << 4) + q16, kc)]);
            const short8 b0 = *reinterpret_cast<const short8*>(&vT[swz64(dbase + q16, kc)]);
            const short8 b1 = *reinterpret_cast<const short8*>(&vT[swz64(dbase + 16 + q16, kc)]);
            o_[0][0] = __builtin_amdgcn_mfma_f32_16x16x32_bf16(a0, b0, o_[0][0], 0, 0, 0);
            o_[0][1] = __builtin_amdgcn_mfma_f32_16x16x32_bf16(a0, b1, o_[0][1], 0, 0, 0);
            o_[1][0] = __builtin_amdgcn_mfma_f32_16x16x32_bf16(a1, b0, o_[1][0], 0, 0, 0);
            o_[1][1] = __builtin_amdgcn_mfma_f32_16x16x32_bf16(a1, b1, o_[1][1], 0, 0, 0);
        }
        __syncthreads();   // all P/vT reads done before o overwrites bufA
        #pragma unroll
        for (int ii = 0; ii < 2; ++ii)
            #pragma unroll
            for (int jo = 0; jo < 2; ++jo)
                #pragma unroll
                for (int r = 0; r < 4; ++r) {
                    const int t = ((i0 + ii) << 4) + (g << 2) + r;
                    bufA[swz64(t, dbase + (jo << 4) + q16)] = f2bf(o_[ii][jo][r]);
                }
        __syncthreads();

        // ===== proj accumulate: out += o_pair[64][64] @ wproj[64p..64p+64][:] =====
        #pragma unroll
        for (int ks = 0; ks < 2; ++ks) {
            const int kc = (ks << 5) + (g << 3);
            const int kglob = (p << 6) + kc;
            short8 aO[4];
            #pragma unroll
            for (int i = 0; i < 4; ++i)
                aO[i] = *reinterpret_cast<const short8*>(&bufA[swz64((i << 4) + q16, kc)]);
            #pragma unroll
            for (int jj = 0; jj < 4; ++jj) {
                const short8 bw = *reinterpret_cast<const short8*>(
                    wprojT + (size_t)((wave << 6) + (jj << 4) + q16) * 256 + kglob);
                #pragma unroll
                for (int i = 0; i < 4; ++i)
                    acc_p[i][jj] = __builtin_amdgcn_mfma_f32_16x16x32_bf16(aO[i], bw, acc_p[i][jj], 0, 0, 0);
            }
        }
        __syncthreads();   // before next pair's qkv epilogue rewrites bufA/bufB/vT
    }

    // ===== epilogue: write out (fp32) with bias =====
    float bp[4];
    #pragma unroll
    for (int jj = 0; jj < 4; ++jj) bp[jj] = bproj[(wave << 6) + (jj << 4) + q16];
    #pragma unroll
    for (int i = 0; i < 4; ++i) {
        #pragma unroll
        for (int r = 0; r < 4; ++r) {
            const int t  = (i << 4) + (g << 2) + r;
            const int hr = (wh << 3) + (t >> 3);
            const int wc = (ww << 3) + (t & 7);
            float* orow = out + (((size_t)b * 256 + hr) * 256 + wc) * 256;
            #pragma unroll
            for (int jj = 0; jj < 4; ++jj)
                orow[(wave << 6) + (jj << 4) + q16] = acc_p[i][jj][r] + bp[jj];
        }
    }
}

extern "C" void kernel_launch(void* const* d_in, const int* in_sizes, int n_in,
                              void* d_out, int out_size, void* d_ws, size_t ws_size,
                              hipStream_t stream) {
    const float* x     = (const float*)d_in[0];
    const float* wqkv  = (const float*)d_in[1];
    const float* bqkv  = (const float*)d_in[2];
    const float* wproj = (const float*)d_in[3];
    const float* bproj = (const float*)d_in[4];
    float* out = (float*)d_out;
    unsigned short* wT = (unsigned short*)d_ws;   // 524288 bytes used

    prep_w<<<1024, 256, 0, stream>>>(wqkv, wproj, wT);
    winattn<<<4096, 256, 0, stream>>>(x, bqkv, bproj, wT, wT + 768 * 256, out);
}